// Round 1
// baseline (828.481 us; speedup 1.0000x reference)
//
#include <hip/hip_runtime.h>
#include <cstddef>

#define VOCAB 32000
#define EMB 32
#define HID 64
#define NG 256      // 4*HID
#define BATCH 1024
#define SEQ 512

__device__ __forceinline__ float sigmoidf_fast(float x) {
  return 1.0f / (1.0f + __expf(-x));
}
__device__ __forceinline__ float tanhf_fast(float x) {
  float a = fabsf(x);
  float e = __expf(-2.0f * a);
  float t = (1.0f - e) / (1.0f + e);   // e <= 1, no overflow
  return copysignf(t, x);
}

// ---------------- Kernel 1: fused embedding+input-proj table ----------------
// table[v][g] = b_ih[g] + b_hh[g] + sum_e emb[v][e] * W_ih[g][e]
#define K1_ROWS 32
__global__ __launch_bounds__(256) void build_table(
    const float* __restrict__ emb, const float* __restrict__ W_ih,
    const float* __restrict__ b_ih, const float* __restrict__ b_hh,
    float* __restrict__ table) {
  __shared__ __align__(16) float erow[K1_ROWS * EMB];
  const int tid = threadIdx.x;
  const int v0 = blockIdx.x * K1_ROWS;

  // this thread's gate row of W_ih in registers
  float w[EMB];
#pragma unroll
  for (int e = 0; e < EMB; e += 4) {
    const float4 t = *(const float4*)&W_ih[tid * EMB + e];
    w[e] = t.x; w[e + 1] = t.y; w[e + 2] = t.z; w[e + 3] = t.w;
  }
  const float bsum = b_ih[tid] + b_hh[tid];

  // cooperative load of 32 emb rows (1024 floats) -> LDS
  ((float4*)erow)[tid] = ((const float4*)&emb[(size_t)v0 * EMB])[tid];
  __syncthreads();

#pragma unroll 4
  for (int r = 0; r < K1_ROWS; ++r) {
    float acc = bsum;
#pragma unroll
    for (int e = 0; e < EMB; ++e) acc += erow[r * EMB + e] * w[e];  // broadcast LDS reads
    table[(size_t)(v0 + r) * NG + tid] = acc;  // coalesced
  }
}

// ---------------- Kernel 2: LSTM recurrence ----------------
// One block (256 threads) per batch element. Thread g owns gate g.
__global__ __launch_bounds__(256) void lstm_seq(
    const int* __restrict__ x, const float* __restrict__ table,
    const float* __restrict__ W_hh, float* __restrict__ h_out) {
  __shared__ int xs[SEQ];
  __shared__ __align__(16) float h_lds[HID];
  __shared__ __align__(16) float gates[NG];
  const int tid = threadIdx.x;
  const int b = blockIdx.x;

  for (int i = tid; i < SEQ; i += 256) xs[i] = x[(size_t)b * SEQ + i];

  // W_hh row for this gate in registers (64 floats)
  float w[HID];
#pragma unroll
  for (int k = 0; k < HID; k += 4) {
    const float4 t = *(const float4*)&W_hh[tid * HID + k];
    w[k] = t.x; w[k + 1] = t.y; w[k + 2] = t.z; w[k + 3] = t.w;
  }
  if (tid < HID) h_lds[tid] = 0.0f;
  float c = 0.0f;
  __syncthreads();

  float xg_cur = table[(size_t)xs[0] * NG + tid];

#pragma unroll 1
  for (int t = 0; t < SEQ; ++t) {
    // prefetch next step's input-gate row (hidden behind matvec)
    float xg_next = 0.0f;
    if (t + 1 < SEQ) xg_next = table[(size_t)xs[t + 1] * NG + tid];

    // gate[g] = xg + h . W_hh[g]
    float acc = xg_cur;
    const float4* h4 = (const float4*)h_lds;
#pragma unroll
    for (int k4 = 0; k4 < HID / 4; ++k4) {
      const float4 hv = h4[k4];  // broadcast read
      acc += hv.x * w[4 * k4] + hv.y * w[4 * k4 + 1] +
             hv.z * w[4 * k4 + 2] + hv.w * w[4 * k4 + 3];
    }
    gates[tid] = acc;
    __syncthreads();

    if (tid < HID) {
      const float gi = sigmoidf_fast(gates[tid]);
      const float gf = sigmoidf_fast(gates[HID + tid]);
      const float gg = tanhf_fast(gates[2 * HID + tid]);
      const float go = sigmoidf_fast(gates[3 * HID + tid]);
      c = gf * c + gi * gg;
      h_lds[tid] = go * tanhf_fast(c);
    }
    xg_cur = xg_next;
    __syncthreads();
  }

  if (tid < HID) h_out[(size_t)b * HID + tid] = h_lds[tid];
}

// ---------------- Kernel 3: FC to vocab ----------------
// out[b][v] = h[b] . fc_W[v] + fc_b[v].  Tile 128b x 128v, K=64 in LDS.
#define FC_BB 128
#define FC_BV 128
#define FC_PAD 4
__global__ __launch_bounds__(256) void fc_kernel(
    const float* __restrict__ h, const float* __restrict__ fc_W,
    const float* __restrict__ fc_b, float* __restrict__ out) {
  __shared__ __align__(16) float sh[HID][FC_BB + FC_PAD];  // h^T tile [k][b]
  __shared__ __align__(16) float sw[HID][FC_BV + FC_PAD];  // w^T tile [k][v]
  const int tid = threadIdx.x;
  const int v0 = blockIdx.x * FC_BV;
  const int b0 = blockIdx.y * FC_BB;
  const int ti = tid >> 4;  // 0..15 (b dir)
  const int tj = tid & 15;  // 0..15 (v dir)

  // bias for this thread's 8 v's
  const float4 bias0 = *(const float4*)&fc_b[v0 + tj * 4];
  const float4 bias1 = *(const float4*)&fc_b[v0 + 64 + tj * 4];

  // stage h tile (transposed): 128 rows x 64 -> sh[k][bl]
  {
    const float4* src = (const float4*)&h[(size_t)b0 * HID];
#pragma unroll
    for (int i = 0; i < 8; ++i) {
      const int idx = tid + i * 256;     // float4 index in [0,2048)
      const float4 t = src[idx];
      const int bl = idx >> 4;           // idx*4/64
      const int k = (idx * 4) & (HID - 1);
      sh[k][bl] = t.x; sh[k + 1][bl] = t.y; sh[k + 2][bl] = t.z; sh[k + 3][bl] = t.w;
    }
    const float4* wsrc = (const float4*)&fc_W[(size_t)v0 * HID];
#pragma unroll
    for (int i = 0; i < 8; ++i) {
      const int idx = tid + i * 256;
      const float4 t = wsrc[idx];
      const int vl = idx >> 4;
      const int k = (idx * 4) & (HID - 1);
      sw[k][vl] = t.x; sw[k + 1][vl] = t.y; sw[k + 2][vl] = t.z; sw[k + 3][vl] = t.w;
    }
  }
  __syncthreads();

  float acc[8][8];
#pragma unroll
  for (int i = 0; i < 8; ++i)
#pragma unroll
    for (int j = 0; j < 8; ++j) acc[i][j] = 0.0f;

#pragma unroll 4
  for (int k = 0; k < HID; ++k) {
    const float4 h0 = *(const float4*)&sh[k][ti * 8];
    const float4 h1 = *(const float4*)&sh[k][ti * 8 + 4];
    const float4 w0 = *(const float4*)&sw[k][tj * 4];
    const float4 w1 = *(const float4*)&sw[k][64 + tj * 4];
    const float hv[8] = {h0.x, h0.y, h0.z, h0.w, h1.x, h1.y, h1.z, h1.w};
    const float wv[8] = {w0.x, w0.y, w0.z, w0.w, w1.x, w1.y, w1.z, w1.w};
#pragma unroll
    for (int i = 0; i < 8; ++i)
#pragma unroll
      for (int j = 0; j < 8; ++j) acc[i][j] += hv[i] * wv[j];
  }

#pragma unroll
  for (int i = 0; i < 8; ++i) {
    const size_t row = (size_t)(b0 + ti * 8 + i) * VOCAB;
    float4 o0, o1;
    o0.x = acc[i][0] + bias0.x; o0.y = acc[i][1] + bias0.y;
    o0.z = acc[i][2] + bias0.z; o0.w = acc[i][3] + bias0.w;
    o1.x = acc[i][4] + bias1.x; o1.y = acc[i][5] + bias1.y;
    o1.z = acc[i][6] + bias1.z; o1.w = acc[i][7] + bias1.w;
    *(float4*)&out[row + v0 + tj * 4] = o0;
    *(float4*)&out[row + v0 + 64 + tj * 4] = o1;
  }
}

extern "C" void kernel_launch(void* const* d_in, const int* in_sizes, int n_in,
                              void* d_out, int out_size, void* d_ws, size_t ws_size,
                              hipStream_t stream) {
  const int* x = (const int*)d_in[0];
  const float* emb = (const float*)d_in[1];
  const float* W_ih = (const float*)d_in[2];
  const float* W_hh = (const float*)d_in[3];
  const float* b_ih = (const float*)d_in[4];
  const float* b_hh = (const float*)d_in[5];
  const float* fc_W = (const float*)d_in[6];
  const float* fc_b = (const float*)d_in[7];
  float* out = (float*)d_out;

  // Scratch plan:
  //  - table (VOCAB*NG floats = 32.77 MB) lives in d_out; it is only read by
  //    lstm_seq, which completes (stream-ordered) before fc_kernel overwrites
  //    all of d_out.
  //  - h_last (BATCH*HID floats = 256 KB) lives in d_ws.
  float* table = out;
  float* hbuf = (float*)d_ws;

  build_table<<<VOCAB / K1_ROWS, 256, 0, stream>>>(emb, W_ih, b_ih, b_hh, table);
  lstm_seq<<<BATCH, 256, 0, stream>>>(x, table, W_hh, hbuf);
  dim3 g3(VOCAB / FC_BV, BATCH / FC_BB);
  fc_kernel<<<g3, 256, 0, stream>>>(hbuf, fc_W, fc_b, out);
}

// Round 2
// 667.099 us; speedup vs baseline: 1.2419x; 1.2419x over previous
//
#include <hip/hip_runtime.h>
#include <cstddef>
#include <cstdint>

#define VOCAB 32000
#define EMB 32
#define HID 64
#define NG 256      // 4*HID
#define BATCH 1024
#define SEQ 512
#define NB 4        // real batch rows per block (MFMA M=16, rows 4..15 padded)
#define ROWB 72     // shorts per Hsplit row: 64 + 8 pad (row stride 144 B -> 2-way bank alias = free)

typedef short short8 __attribute__((ext_vector_type(8)));
typedef float floatx4 __attribute__((ext_vector_type(4)));
typedef int int4v __attribute__((ext_vector_type(4)));

union Frag {
  short8 s;
  int4v v;
};

__device__ __forceinline__ float fast_sig(float x) {
  return __builtin_amdgcn_rcpf(1.0f + __expf(-x));
}
__device__ __forceinline__ float fast_tanh(float x) {
  // 1 - 2/(e^{2x}+1); saturates correctly at +-inf via rcp(inf)=0
  return fmaf(-2.0f, __builtin_amdgcn_rcpf(__expf(2.0f * x) + 1.0f), 1.0f);
}

// ---------------- Kernel 1: fused embedding+input-proj table ----------------
// table[v][g] = b_ih[g] + b_hh[g] + sum_e emb[v][e] * W_ih[g][e]
#define K1_ROWS 32
__global__ __launch_bounds__(256) void build_table(
    const float* __restrict__ emb, const float* __restrict__ W_ih,
    const float* __restrict__ b_ih, const float* __restrict__ b_hh,
    float* __restrict__ table) {
  __shared__ __align__(16) float erow[K1_ROWS * EMB];
  const int tid = threadIdx.x;
  const int v0 = blockIdx.x * K1_ROWS;

  float w[EMB];
#pragma unroll
  for (int e = 0; e < EMB; e += 4) {
    const float4 t = *(const float4*)&W_ih[tid * EMB + e];
    w[e] = t.x; w[e + 1] = t.y; w[e + 2] = t.z; w[e + 3] = t.w;
  }
  const float bsum = b_ih[tid] + b_hh[tid];

  ((float4*)erow)[tid] = ((const float4*)&emb[(size_t)v0 * EMB])[tid];
  __syncthreads();

#pragma unroll 4
  for (int r = 0; r < K1_ROWS; ++r) {
    float acc = bsum;
#pragma unroll
    for (int e = 0; e < EMB; ++e) acc += erow[r * EMB + e] * w[e];
    table[(size_t)(v0 + r) * NG + tid] = acc;
  }
}

// ---------------- Kernel 2: LSTM recurrence via MFMA ----------------
// Grid: BATCH/NB = 256 blocks x 256 threads (4 waves).
// Block handles NB=4 real batch rows inside an M=16 MFMA tile.
// Wave w owns gate-tiles {w, w+4, w+8, w+12} => lane holds i,f,g,o for the
// same (batch,hid) across its 4 accumulators; c/h update is fully in-lane.
// W_hh is split hi/lo bf16 (3-product split GEMM => fp32-grade accuracy).
__global__ __launch_bounds__(256) void lstm_mfma(
    const int* __restrict__ x, const float* __restrict__ table,
    const float* __restrict__ W_hh, float* __restrict__ h_out) {
  __shared__ __align__(16) short Hs[2][2][16 * ROWB];  // [buf][hi/lo][row][hid]
  __shared__ int xls[NB * SEQ];

  const int tid = threadIdx.x;
  const int w = tid >> 6;       // wave 0..3
  const int lane = tid & 63;
  const int quad = lane >> 4;   // 0..3
  const int col = lane & 15;    // MFMA n-col (gate within tile) / A m-row
  const int blk = blockIdx.x;
  const int myhid = w * 16 + col;

  // zero H buffers (padded rows must be finite)
  {
    int* hz = (int*)&Hs[0][0][0];
    const int nz = 2 * 2 * 16 * ROWB / 2;
#pragma unroll
    for (int i = tid; i < nz; i += 256) hz[i] = 0;
  }
  // stage this block's token ids
  {
    const int* xsrc = &x[(size_t)blk * NB * SEQ];
    for (int i = tid; i < NB * SEQ; i += 256) xls[i] = xsrc[i];
  }

  // resident W_hh fragments: B[k][n] with n = tile*16+col, k = ko*32+quad*8+j
  Frag Bhi[4][2], Blo[4][2];
#pragma unroll
  for (int ti = 0; ti < 4; ++ti) {
    const int n = (w + ti * 4) * 16 + col;
#pragma unroll
    for (int ko = 0; ko < 2; ++ko) {
      const float* src = &W_hh[n * HID + ko * 32 + quad * 8];
#pragma unroll
      for (int j = 0; j < 8; ++j) {
        const float f = src[j];
        const unsigned fb = __float_as_uint(f);
        Bhi[ti][ko].s[j] = (short)(fb >> 16);
        const float hif = __uint_as_float(fb & 0xffff0000u);
        Blo[ti][ko].s[j] = (short)(__float_as_uint(f - hif) >> 16);
      }
    }
  }

  float xg_cur[4][4], xg_nxt[4][4];
#pragma unroll
  for (int ti = 0; ti < 4; ++ti)
#pragma unroll
    for (int r = 0; r < 4; ++r) { xg_cur[ti][r] = 0.0f; xg_nxt[ti][r] = 0.0f; }

  float c[4] = {0.0f, 0.0f, 0.0f, 0.0f};
  float hreg[4] = {0.0f, 0.0f, 0.0f, 0.0f};

  __syncthreads();  // xls/Hs visible

  // prefetch xg for t=0 (only real rows: quad 0 -> batch rows 0..3)
  if (quad == 0) {
#pragma unroll
    for (int r = 0; r < 4; ++r) {
      const int xr = xls[r * SEQ];
#pragma unroll
      for (int ti = 0; ti < 4; ++ti)
        xg_cur[ti][r] = table[(size_t)xr * NG + (w + ti * 4) * 16 + col];
    }
  }

  for (int t = 0; t < SEQ; ++t) {
    const int p = t & 1;

    // A fragments: A[m=col][k = ko*32 + quad*8 + j], hi & lo splits
    Frag Ahi0, Ahi1, Alo0, Alo1;
    {
      const int abase = col * ROWB + quad * 8;
      Ahi0.v = *(const int4v*)&Hs[p][0][abase];
      Ahi1.v = *(const int4v*)&Hs[p][0][abase + 32];
      Alo0.v = *(const int4v*)&Hs[p][1][abase];
      Alo1.v = *(const int4v*)&Hs[p][1][abase + 32];
    }

    floatx4 acc[4];
#pragma unroll
    for (int ti = 0; ti < 4; ++ti) {
      floatx4 a;
      a[0] = xg_cur[ti][0]; a[1] = xg_cur[ti][1];
      a[2] = xg_cur[ti][2]; a[3] = xg_cur[ti][3];
      a = __builtin_amdgcn_mfma_f32_16x16x32_bf16(Ahi0.s, Bhi[ti][0].s, a, 0, 0, 0);
      a = __builtin_amdgcn_mfma_f32_16x16x32_bf16(Ahi1.s, Bhi[ti][1].s, a, 0, 0, 0);
      a = __builtin_amdgcn_mfma_f32_16x16x32_bf16(Ahi0.s, Blo[ti][0].s, a, 0, 0, 0);
      a = __builtin_amdgcn_mfma_f32_16x16x32_bf16(Ahi1.s, Blo[ti][1].s, a, 0, 0, 0);
      a = __builtin_amdgcn_mfma_f32_16x16x32_bf16(Alo0.s, Bhi[ti][0].s, a, 0, 0, 0);
      a = __builtin_amdgcn_mfma_f32_16x16x32_bf16(Alo1.s, Bhi[ti][1].s, a, 0, 0, 0);
      acc[ti] = a;
    }

    // prefetch next step's xg rows while MFMA/activations run
    {
      const int tn = (t + 1 < SEQ) ? t + 1 : SEQ - 1;
      if (quad == 0) {
#pragma unroll
        for (int r = 0; r < 4; ++r) {
          const int xr = xls[r * SEQ + tn];
#pragma unroll
          for (int ti = 0; ti < 4; ++ti)
            xg_nxt[ti][r] = table[(size_t)xr * NG + (w + ti * 4) * 16 + col];
        }
      }
    }

    // in-lane LSTM cell update; write h (hi/lo split) to the other buffer
    {
      short* dsthi = &Hs[p ^ 1][0][myhid];
      short* dstlo = &Hs[p ^ 1][1][myhid];
#pragma unroll
      for (int r = 0; r < 4; ++r) {
        const float gi = fast_sig(acc[0][r]);
        const float gf = fast_sig(acc[1][r]);
        const float gg = fast_tanh(acc[2][r]);
        const float go = fast_sig(acc[3][r]);
        c[r] = gf * c[r] + gi * gg;
        const float h = go * fast_tanh(c[r]);
        hreg[r] = h;
        const unsigned hb = __float_as_uint(h);
        const float hif = __uint_as_float(hb & 0xffff0000u);
        const int row = quad * 4 + r;
        dsthi[row * ROWB] = (short)(hb >> 16);
        dstlo[row * ROWB] = (short)(__float_as_uint(h - hif) >> 16);
      }
    }
    __syncthreads();

#pragma unroll
    for (int ti = 0; ti < 4; ++ti)
#pragma unroll
      for (int r = 0; r < 4; ++r) xg_cur[ti][r] = xg_nxt[ti][r];
  }

  if (quad == 0) {
#pragma unroll
    for (int r = 0; r < 4; ++r)
      h_out[((size_t)blk * NB + r) * HID + myhid] = hreg[r];
  }
}

// ---------------- Kernel 3: FC to vocab ----------------
#define FC_BB 128
#define FC_BV 128
#define FC_PAD 4
__global__ __launch_bounds__(256) void fc_kernel(
    const float* __restrict__ h, const float* __restrict__ fc_W,
    const float* __restrict__ fc_b, float* __restrict__ out) {
  __shared__ __align__(16) float sh[HID][FC_BB + FC_PAD];
  __shared__ __align__(16) float sw[HID][FC_BV + FC_PAD];
  const int tid = threadIdx.x;
  const int v0 = blockIdx.x * FC_BV;
  const int b0 = blockIdx.y * FC_BB;
  const int ti = tid >> 4;
  const int tj = tid & 15;

  const float4 bias0 = *(const float4*)&fc_b[v0 + tj * 4];
  const float4 bias1 = *(const float4*)&fc_b[v0 + 64 + tj * 4];

  {
    const float4* src = (const float4*)&h[(size_t)b0 * HID];
#pragma unroll
    for (int i = 0; i < 8; ++i) {
      const int idx = tid + i * 256;
      const float4 t = src[idx];
      const int bl = idx >> 4;
      const int k = (idx * 4) & (HID - 1);
      sh[k][bl] = t.x; sh[k + 1][bl] = t.y; sh[k + 2][bl] = t.z; sh[k + 3][bl] = t.w;
    }
    const float4* wsrc = (const float4*)&fc_W[(size_t)v0 * HID];
#pragma unroll
    for (int i = 0; i < 8; ++i) {
      const int idx = tid + i * 256;
      const float4 t = wsrc[idx];
      const int vl = idx >> 4;
      const int k = (idx * 4) & (HID - 1);
      sw[k][vl] = t.x; sw[k + 1][vl] = t.y; sw[k + 2][vl] = t.z; sw[k + 3][vl] = t.w;
    }
  }
  __syncthreads();

  float acc[8][8];
#pragma unroll
  for (int i = 0; i < 8; ++i)
#pragma unroll
    for (int j = 0; j < 8; ++j) acc[i][j] = 0.0f;

#pragma unroll 4
  for (int k = 0; k < HID; ++k) {
    const float4 h0 = *(const float4*)&sh[k][ti * 8];
    const float4 h1 = *(const float4*)&sh[k][ti * 8 + 4];
    const float4 w0 = *(const float4*)&sw[k][tj * 4];
    const float4 w1 = *(const float4*)&sw[k][64 + tj * 4];
    const float hv[8] = {h0.x, h0.y, h0.z, h0.w, h1.x, h1.y, h1.z, h1.w};
    const float wv[8] = {w0.x, w0.y, w0.z, w0.w, w1.x, w1.y, w1.z, w1.w};
#pragma unroll
    for (int i = 0; i < 8; ++i)
#pragma unroll
      for (int j = 0; j < 8; ++j) acc[i][j] += hv[i] * wv[j];
  }

#pragma unroll
  for (int i = 0; i < 8; ++i) {
    const size_t row = (size_t)(b0 + ti * 8 + i) * VOCAB;
    float4 o0, o1;
    o0.x = acc[i][0] + bias0.x; o0.y = acc[i][1] + bias0.y;
    o0.z = acc[i][2] + bias0.z; o0.w = acc[i][3] + bias0.w;
    o1.x = acc[i][4] + bias1.x; o1.y = acc[i][5] + bias1.y;
    o1.z = acc[i][6] + bias1.z; o1.w = acc[i][7] + bias1.w;
    *(float4*)&out[row + v0 + tj * 4] = o0;
    *(float4*)&out[row + v0 + 64 + tj * 4] = o1;
  }
}

extern "C" void kernel_launch(void* const* d_in, const int* in_sizes, int n_in,
                              void* d_out, int out_size, void* d_ws, size_t ws_size,
                              hipStream_t stream) {
  const int* x = (const int*)d_in[0];
  const float* emb = (const float*)d_in[1];
  const float* W_ih = (const float*)d_in[2];
  const float* W_hh = (const float*)d_in[3];
  const float* b_ih = (const float*)d_in[4];
  const float* b_hh = (const float*)d_in[5];
  const float* fc_W = (const float*)d_in[6];
  const float* fc_b = (const float*)d_in[7];
  float* out = (float*)d_out;

  // table (32.77 MB) lives in d_out: read only by lstm_mfma, which completes
  // (stream-ordered) before fc_kernel overwrites d_out. h_last in d_ws.
  float* table = out;
  float* hbuf = (float*)d_ws;

  build_table<<<VOCAB / K1_ROWS, 256, 0, stream>>>(emb, W_ih, b_ih, b_hh, table);
  lstm_mfma<<<BATCH / NB, 256, 0, stream>>>(x, table, W_hh, hbuf);
  dim3 g3(VOCAB / FC_BV, BATCH / FC_BB);
  fc_kernel<<<g3, 256, 0, stream>>>(hbuf, fc_W, fc_b, out);
}

// Round 3
// 431.708 us; speedup vs baseline: 1.9191x; 1.5453x over previous
//
#include <hip/hip_runtime.h>
#include <cstddef>
#include <cstdint>

#define VOCAB 32000
#define EMB 32
#define HID 64
#define NG 256      // 4*HID
#define BATCH 1024
#define SEQ 512
#define NB 4        // real batch rows per block, mapped to M-rows 0,4,8,12
#define ROWB 72     // shorts per Hsplit row: 64 + 8 pad (row stride 144 B)

typedef short short8 __attribute__((ext_vector_type(8)));
typedef float floatx4 __attribute__((ext_vector_type(4)));
typedef int int4v __attribute__((ext_vector_type(4)));

union Frag {
  short8 s;
  int4v v;
};

__device__ __forceinline__ float fast_sig(float x) {
  return __builtin_amdgcn_rcpf(1.0f + __expf(-x));
}
__device__ __forceinline__ float fast_tanh(float x) {
  // 1 - 2/(e^{2x}+1); saturates correctly at +-inf via rcp(inf)=0
  return fmaf(-2.0f, __builtin_amdgcn_rcpf(__expf(2.0f * x) + 1.0f), 1.0f);
}

// ---------------- Kernel 1: fused embedding+input-proj table ----------------
// table[v][g] = b_ih[g] + b_hh[g] + sum_e emb[v][e] * W_ih[g][e]
#define K1_ROWS 32
__global__ __launch_bounds__(256) void build_table(
    const float* __restrict__ emb, const float* __restrict__ W_ih,
    const float* __restrict__ b_ih, const float* __restrict__ b_hh,
    float* __restrict__ table) {
  __shared__ __align__(16) float erow[K1_ROWS * EMB];
  const int tid = threadIdx.x;
  const int v0 = blockIdx.x * K1_ROWS;

  float w[EMB];
#pragma unroll
  for (int e = 0; e < EMB; e += 4) {
    const float4 t = *(const float4*)&W_ih[tid * EMB + e];
    w[e] = t.x; w[e + 1] = t.y; w[e + 2] = t.z; w[e + 3] = t.w;
  }
  const float bsum = b_ih[tid] + b_hh[tid];

  ((float4*)erow)[tid] = ((const float4*)&emb[(size_t)v0 * EMB])[tid];
  __syncthreads();

#pragma unroll 4
  for (int r = 0; r < K1_ROWS; ++r) {
    float acc = bsum;
#pragma unroll
    for (int e = 0; e < EMB; ++e) acc += erow[r * EMB + e] * w[e];
    table[(size_t)(v0 + r) * NG + tid] = acc;
  }
}

// ---------------- Kernel 2: LSTM recurrence via MFMA ----------------
// Grid: BATCH/NB = 256 blocks x 256 threads (4 waves).
// Real batch rows sit at M-rows 0,4,8,12 (one per quad, acc reg 0), so every
// lane owns exactly one (batch,hid) state: activations/c-update are 1
// state/lane, junk M-rows are never written (stay exactly zero in LDS, so
// their MFMA outputs D=C=0 forever). W_hh in hi/lo bf16 3-product split.
// xg gather is prefetched 2 steps ahead via ping-pong register sets (t%2).
__global__ __launch_bounds__(256) void lstm_mfma(
    const int* __restrict__ x, const float* __restrict__ table,
    const float* __restrict__ W_hh, float* __restrict__ h_out) {
  __shared__ __align__(16) short Hs[2][2][16 * ROWB];  // [buf][hi/lo][row][hid]
  __shared__ int xls[NB * SEQ];

  const int tid = threadIdx.x;
  const int w = tid >> 6;       // wave 0..3
  const int lane = tid & 63;
  const int quad = lane >> 4;   // 0..3  -> owns batch row blk*4+quad (M-row 4*quad)
  const int col = lane & 15;    // MFMA n-col / A m-row
  const int blk = blockIdx.x;
  const int myhid = w * 16 + col;

  // zero H buffers (junk rows must stay exactly zero)
  {
    int* hz = (int*)&Hs[0][0][0];
    const int nz = (int)(sizeof(Hs) / 4);
    for (int i = tid; i < nz; i += 256) hz[i] = 0;
  }
  // stage this block's token ids
  {
    const int* xsrc = &x[(size_t)blk * NB * SEQ];
    for (int i = tid; i < NB * SEQ; i += 256) xls[i] = xsrc[i];
  }

  // resident W_hh fragments: B[k][n] with n = (w+ti*4)*16+col, k = ko*32+quad*8+j
  Frag Bhi[4][2], Blo[4][2];
#pragma unroll
  for (int ti = 0; ti < 4; ++ti) {
    const int n = (w + ti * 4) * 16 + col;
#pragma unroll
    for (int ko = 0; ko < 2; ++ko) {
      const float* src = &W_hh[n * HID + ko * 32 + quad * 8];
#pragma unroll
      for (int j = 0; j < 8; ++j) {
        const float f = src[j];
        const unsigned fb = __float_as_uint(f);
        Bhi[ti][ko].s[j] = (short)(fb >> 16);
        const float hif = __uint_as_float(fb & 0xffff0000u);
        Blo[ti][ko].s[j] = (short)(__float_as_uint(f - hif) >> 16);
      }
    }
  }

  floatx4 acc[4];
#pragma unroll
  for (int ti = 0; ti < 4; ++ti) acc[ti] = (floatx4){0.f, 0.f, 0.f, 0.f};

  float c = 0.0f, hcur = 0.0f;

  __syncthreads();  // xls/Hs visible

  const int xrow = quad * SEQ;
  const float* __restrict__ tb = table + myhid;

  float xgA[4], xgB[4];
  // prologue: gather xg for t=0 and t=1
  {
    const float* bp = tb + ((size_t)(unsigned)xls[xrow + 0] << 8);
#pragma unroll
    for (int ti = 0; ti < 4; ++ti) xgA[ti] = bp[ti * 64];
    const float* bq = tb + ((size_t)(unsigned)xls[xrow + 1] << 8);
#pragma unroll
    for (int ti = 0; ti < 4; ++ti) xgB[ti] = bq[ti * 64];
  }

  auto step = [&](float (&XG)[4], const int RB, const int TT) {
    // A fragments: A[m=col][k = ko*32 + quad*8 + j], hi & lo splits
    const int abase = col * ROWB + quad * 8;
    Frag Ahi0, Ahi1, Alo0, Alo1;
    Ahi0.v = *(const int4v*)&Hs[RB][0][abase];
    Ahi1.v = *(const int4v*)&Hs[RB][0][abase + 32];
    Alo0.v = *(const int4v*)&Hs[RB][1][abase];
    Alo1.v = *(const int4v*)&Hs[RB][1][abase + 32];

#pragma unroll
    for (int ti = 0; ti < 4; ++ti) {
      floatx4 a = acc[ti];
      a[0] = XG[ti];  // regs 1..3 remain exactly 0 (junk rows: A rows are 0)
      a = __builtin_amdgcn_mfma_f32_16x16x32_bf16(Ahi0.s, Bhi[ti][0].s, a, 0, 0, 0);
      a = __builtin_amdgcn_mfma_f32_16x16x32_bf16(Ahi1.s, Bhi[ti][1].s, a, 0, 0, 0);
      a = __builtin_amdgcn_mfma_f32_16x16x32_bf16(Ahi0.s, Blo[ti][0].s, a, 0, 0, 0);
      a = __builtin_amdgcn_mfma_f32_16x16x32_bf16(Ahi1.s, Blo[ti][1].s, a, 0, 0, 0);
      a = __builtin_amdgcn_mfma_f32_16x16x32_bf16(Alo0.s, Bhi[ti][0].s, a, 0, 0, 0);
      a = __builtin_amdgcn_mfma_f32_16x16x32_bf16(Alo1.s, Bhi[ti][1].s, a, 0, 0, 0);
      acc[ti] = a;
    }

    // issue gather for step TT+2 into the register set just consumed
    {
      const int tn = (TT + 2 < SEQ) ? TT + 2 : SEQ - 1;
      const float* bp = tb + ((size_t)(unsigned)xls[xrow + tn] << 8);
#pragma unroll
      for (int ti = 0; ti < 4; ++ti) XG[ti] = bp[ti * 64];
    }

    // one real state per lane: (batch=blk*4+quad, hid=myhid) at acc reg 0
    {
      const float gi = fast_sig(acc[0][0]);
      const float gf = fast_sig(acc[1][0]);
      const float gg = fast_tanh(acc[2][0]);
      const float go = fast_sig(acc[3][0]);
      c = gf * c + gi * gg;
      hcur = go * fast_tanh(c);
      const unsigned hb = __float_as_uint(hcur);
      const float hif = __uint_as_float(hb & 0xffff0000u);
      const int hoff = (quad * 4) * ROWB + myhid;  // M-row 4*quad
      Hs[RB ^ 1][0][hoff] = (short)(hb >> 16);
      Hs[RB ^ 1][1][hoff] = (short)(__float_as_uint(hcur - hif) >> 16);
    }
    __syncthreads();
  };

  for (int t = 0; t < SEQ; t += 2) {
    step(xgA, 0, t);
    step(xgB, 1, t + 1);
  }

  h_out[((size_t)blk * NB + quad) * HID + myhid] = hcur;
}

// ---------------- Kernel 3: FC to vocab ----------------
#define FC_BB 128
#define FC_BV 128
#define FC_PAD 4
__global__ __launch_bounds__(256) void fc_kernel(
    const float* __restrict__ h, const float* __restrict__ fc_W,
    const float* __restrict__ fc_b, float* __restrict__ out) {
  __shared__ __align__(16) float sh[HID][FC_BB + FC_PAD];
  __shared__ __align__(16) float sw[HID][FC_BV + FC_PAD];
  const int tid = threadIdx.x;
  const int v0 = blockIdx.x * FC_BV;
  const int b0 = blockIdx.y * FC_BB;
  const int ti = tid >> 4;
  const int tj = tid & 15;

  const float4 bias0 = *(const float4*)&fc_b[v0 + tj * 4];
  const float4 bias1 = *(const float4*)&fc_b[v0 + 64 + tj * 4];

  {
    const float4* src = (const float4*)&h[(size_t)b0 * HID];
#pragma unroll
    for (int i = 0; i < 8; ++i) {
      const int idx = tid + i * 256;
      const float4 t = src[idx];
      const int bl = idx >> 4;
      const int k = (idx * 4) & (HID - 1);
      sh[k][bl] = t.x; sh[k + 1][bl] = t.y; sh[k + 2][bl] = t.z; sh[k + 3][bl] = t.w;
    }
    const float4* wsrc = (const float4*)&fc_W[(size_t)v0 * HID];
#pragma unroll
    for (int i = 0; i < 8; ++i) {
      const int idx = tid + i * 256;
      const float4 t = wsrc[idx];
      const int vl = idx >> 4;
      const int k = (idx * 4) & (HID - 1);
      sw[k][vl] = t.x; sw[k + 1][vl] = t.y; sw[k + 2][vl] = t.z; sw[k + 3][vl] = t.w;
    }
  }
  __syncthreads();

  float acc[8][8];
#pragma unroll
  for (int i = 0; i < 8; ++i)
#pragma unroll
    for (int j = 0; j < 8; ++j) acc[i][j] = 0.0f;

#pragma unroll 4
  for (int k = 0; k < HID; ++k) {
    const float4 h0 = *(const float4*)&sh[k][ti * 8];
    const float4 h1 = *(const float4*)&sh[k][ti * 8 + 4];
    const float4 w0 = *(const float4*)&sw[k][tj * 4];
    const float4 w1 = *(const float4*)&sw[k][64 + tj * 4];
    const float hv[8] = {h0.x, h0.y, h0.z, h0.w, h1.x, h1.y, h1.z, h1.w};
    const float wv[8] = {w0.x, w0.y, w0.z, w0.w, w1.x, w1.y, w1.z, w1.w};
#pragma unroll
    for (int i = 0; i < 8; ++i)
#pragma unroll
      for (int j = 0; j < 8; ++j) acc[i][j] += hv[i] * wv[j];
  }

#pragma unroll
  for (int i = 0; i < 8; ++i) {
    const size_t row = (size_t)(b0 + ti * 8 + i) * VOCAB;
    float4 o0, o1;
    o0.x = acc[i][0] + bias0.x; o0.y = acc[i][1] + bias0.y;
    o0.z = acc[i][2] + bias0.z; o0.w = acc[i][3] + bias0.w;
    o1.x = acc[i][4] + bias1.x; o1.y = acc[i][5] + bias1.y;
    o1.z = acc[i][6] + bias1.z; o1.w = acc[i][7] + bias1.w;
    *(float4*)&out[row + v0 + tj * 4] = o0;
    *(float4*)&out[row + v0 + 64 + tj * 4] = o1;
  }
}

extern "C" void kernel_launch(void* const* d_in, const int* in_sizes, int n_in,
                              void* d_out, int out_size, void* d_ws, size_t ws_size,
                              hipStream_t stream) {
  const int* x = (const int*)d_in[0];
  const float* emb = (const float*)d_in[1];
  const float* W_ih = (const float*)d_in[2];
  const float* W_hh = (const float*)d_in[3];
  const float* b_ih = (const float*)d_in[4];
  const float* b_hh = (const float*)d_in[5];
  const float* fc_W = (const float*)d_in[6];
  const float* fc_b = (const float*)d_in[7];
  float* out = (float*)d_out;

  // table (32.77 MB) lives in d_out: read only by lstm_mfma, which completes
  // (stream-ordered) before fc_kernel overwrites d_out. h_last in d_ws.
  float* table = out;
  float* hbuf = (float*)d_ws;

  build_table<<<VOCAB / K1_ROWS, 256, 0, stream>>>(emb, W_ih, b_ih, b_hh, table);
  lstm_mfma<<<BATCH / NB, 256, 0, stream>>>(x, table, W_hh, hbuf);
  dim3 g3(VOCAB / FC_BV, BATCH / FC_BB);
  fc_kernel<<<g3, 256, 0, stream>>>(hbuf, fc_W, fc_b, out);
}

// Round 4
// 361.530 us; speedup vs baseline: 2.2916x; 1.1941x over previous
//
#include <hip/hip_runtime.h>
#include <cstddef>
#include <cstdint>

#define VOCAB 32000
#define EMB 32
#define HID 64
#define NG 256      // 4*HID
#define BATCH 1024
#define SEQ 512
#define NB 4        // real batch rows per block, mapped to M-rows 0,4,8,12
#define ROWB 72     // halfs per H row: 64 + 8 pad (row stride 144 B)

typedef short short8 __attribute__((ext_vector_type(8)));
typedef _Float16 half8 __attribute__((ext_vector_type(8)));
typedef float floatx4 __attribute__((ext_vector_type(4)));
typedef int int4v __attribute__((ext_vector_type(4)));

union FragH {
  half8 h;
  int4v v;
};

__device__ __forceinline__ float fast_sig(float x) {
  return __builtin_amdgcn_rcpf(1.0f + __expf(-x));
}
__device__ __forceinline__ float fast_tanh(float x) {
  // 1 - 2/(e^{2x}+1); saturates correctly at +-inf via rcp(inf)=0
  return fmaf(-2.0f, __builtin_amdgcn_rcpf(__expf(2.0f * x) + 1.0f), 1.0f);
}

// ---------------- Kernel 1: fused embedding+input-proj table ----------------
// table[v][g] = b_ih[g] + b_hh[g] + sum_e emb[v][e] * W_ih[g][e]
#define K1_ROWS 32
__global__ __launch_bounds__(256) void build_table(
    const float* __restrict__ emb, const float* __restrict__ W_ih,
    const float* __restrict__ b_ih, const float* __restrict__ b_hh,
    float* __restrict__ table) {
  __shared__ __align__(16) float erow[K1_ROWS * EMB];
  const int tid = threadIdx.x;
  const int v0 = blockIdx.x * K1_ROWS;

  float w[EMB];
#pragma unroll
  for (int e = 0; e < EMB; e += 4) {
    const float4 t = *(const float4*)&W_ih[tid * EMB + e];
    w[e] = t.x; w[e + 1] = t.y; w[e + 2] = t.z; w[e + 3] = t.w;
  }
  const float bsum = b_ih[tid] + b_hh[tid];

  ((float4*)erow)[tid] = ((const float4*)&emb[(size_t)v0 * EMB])[tid];
  __syncthreads();

#pragma unroll 4
  for (int r = 0; r < K1_ROWS; ++r) {
    float acc = bsum;
#pragma unroll
    for (int e = 0; e < EMB; ++e) acc += erow[r * EMB + e] * w[e];
    table[(size_t)(v0 + r) * NG + tid] = acc;
  }
}

// ---------------- Kernel 2: LSTM recurrence via MFMA (fp16 single-product) --
// Grid: BATCH/NB = 256 blocks x 256 threads (4 waves).
// Real batch rows at M-rows 0,4,8,12 (one per quad, acc reg 0): each lane owns
// exactly one (batch,hid) state. Junk M-rows never written -> stay exactly 0.
// W_hh and h in fp16 (rel err ~2^-11, fp32 accumulate): 8 MFMA/wave/step.
// xg gather prefetched 2 steps ahead via ping-pong register sets.
__global__ __launch_bounds__(256) void lstm_mfma(
    const int* __restrict__ x, const float* __restrict__ table,
    const float* __restrict__ W_hh, float* __restrict__ h_out) {
  __shared__ __align__(16) _Float16 Hs[2][16 * ROWB];  // [buf][row][hid]
  __shared__ int xls[NB * SEQ];

  const int tid = threadIdx.x;
  const int w = tid >> 6;       // wave 0..3
  const int lane = tid & 63;
  const int quad = lane >> 4;   // 0..3 -> owns batch row blk*4+quad (M-row 4*quad)
  const int col = lane & 15;    // MFMA n-col / A m-row
  const int blk = blockIdx.x;
  const int myhid = w * 16 + col;

  // zero H buffers (junk rows must stay exactly zero)
  {
    int* hz = (int*)&Hs[0][0];
    const int nz = (int)(sizeof(Hs) / 4);
    for (int i = tid; i < nz; i += 256) hz[i] = 0;
  }
  // stage this block's token ids
  {
    const int* xsrc = &x[(size_t)blk * NB * SEQ];
    for (int i = tid; i < NB * SEQ; i += 256) xls[i] = xsrc[i];
  }

  // resident W_hh fragments (fp16): B[k][n], n = (w+ti*4)*16+col, k = ko*32+quad*8+j
  FragH Bf[4][2];
#pragma unroll
  for (int ti = 0; ti < 4; ++ti) {
    const int n = (w + ti * 4) * 16 + col;
#pragma unroll
    for (int ko = 0; ko < 2; ++ko) {
      const float* src = &W_hh[n * HID + ko * 32 + quad * 8];
#pragma unroll
      for (int j = 0; j < 8; ++j) Bf[ti][ko].h[j] = (_Float16)src[j];
    }
  }

  floatx4 acc[4];
#pragma unroll
  for (int ti = 0; ti < 4; ++ti) acc[ti] = (floatx4){0.f, 0.f, 0.f, 0.f};

  float c = 0.0f, hcur = 0.0f;

  __syncthreads();  // xls/Hs visible

  const int xrow = quad * SEQ;
  const float* __restrict__ tb = table + myhid;

  float xgA[4], xgB[4];
  // prologue: gather xg for t=0 and t=1
  {
    const float* bp = tb + ((size_t)(unsigned)xls[xrow + 0] << 8);
#pragma unroll
    for (int ti = 0; ti < 4; ++ti) xgA[ti] = bp[ti * 64];
    const float* bq = tb + ((size_t)(unsigned)xls[xrow + 1] << 8);
#pragma unroll
    for (int ti = 0; ti < 4; ++ti) xgB[ti] = bq[ti * 64];
  }

  auto step = [&](float (&XG)[4], const int RB, const int TT) {
    // A fragments: A[m=col][k = ko*32 + quad*8 + j]
    const int abase = col * ROWB + quad * 8;
    FragH A0, A1;
    A0.v = *(const int4v*)&Hs[RB][abase];
    A1.v = *(const int4v*)&Hs[RB][abase + 32];

#pragma unroll
    for (int ti = 0; ti < 4; ++ti) {
      floatx4 a = acc[ti];
      a[0] = XG[ti];  // regs 1..3 remain exactly 0 (junk rows: A rows are 0)
      a = __builtin_amdgcn_mfma_f32_16x16x32_f16(A0.h, Bf[ti][0].h, a, 0, 0, 0);
      a = __builtin_amdgcn_mfma_f32_16x16x32_f16(A1.h, Bf[ti][1].h, a, 0, 0, 0);
      acc[ti] = a;
    }

    // issue gather for step TT+2 into the register set just consumed
    {
      const int tn = (TT + 2 < SEQ) ? TT + 2 : SEQ - 1;
      const float* bp = tb + ((size_t)(unsigned)xls[xrow + tn] << 8);
#pragma unroll
      for (int ti = 0; ti < 4; ++ti) XG[ti] = bp[ti * 64];
    }

    // one real state per lane: (batch=blk*4+quad, hid=myhid) at acc reg 0
    {
      const float gi = fast_sig(acc[0][0]);
      const float gf = fast_sig(acc[1][0]);
      const float gg = fast_tanh(acc[2][0]);
      const float go = fast_sig(acc[3][0]);
      c = gf * c + gi * gg;
      hcur = go * fast_tanh(c);
      Hs[RB ^ 1][(quad * 4) * ROWB + myhid] = (_Float16)hcur;  // M-row 4*quad
    }
    __syncthreads();
  };

  for (int t = 0; t < SEQ; t += 2) {
    step(xgA, 0, t);
    step(xgB, 1, t + 1);
  }

  h_out[((size_t)blk * NB + quad) * HID + myhid] = hcur;
}

// ---------------- Kernel 3: FC to vocab ----------------
#define FC_BB 128
#define FC_BV 128
#define FC_PAD 4
__global__ __launch_bounds__(256) void fc_kernel(
    const float* __restrict__ h, const float* __restrict__ fc_W,
    const float* __restrict__ fc_b, float* __restrict__ out) {
  __shared__ __align__(16) float sh[HID][FC_BB + FC_PAD];
  __shared__ __align__(16) float sw[HID][FC_BV + FC_PAD];
  const int tid = threadIdx.x;
  const int v0 = blockIdx.x * FC_BV;
  const int b0 = blockIdx.y * FC_BB;
  const int ti = tid >> 4;
  const int tj = tid & 15;

  const float4 bias0 = *(const float4*)&fc_b[v0 + tj * 4];
  const float4 bias1 = *(const float4*)&fc_b[v0 + 64 + tj * 4];

  {
    const float4* src = (const float4*)&h[(size_t)b0 * HID];
#pragma unroll
    for (int i = 0; i < 8; ++i) {
      const int idx = tid + i * 256;
      const float4 t = src[idx];
      const int bl = idx >> 4;
      const int k = (idx * 4) & (HID - 1);
      sh[k][bl] = t.x; sh[k + 1][bl] = t.y; sh[k + 2][bl] = t.z; sh[k + 3][bl] = t.w;
    }
    const float4* wsrc = (const float4*)&fc_W[(size_t)v0 * HID];
#pragma unroll
    for (int i = 0; i < 8; ++i) {
      const int idx = tid + i * 256;
      const float4 t = wsrc[idx];
      const int vl = idx >> 4;
      const int k = (idx * 4) & (HID - 1);
      sw[k][vl] = t.x; sw[k + 1][vl] = t.y; sw[k + 2][vl] = t.z; sw[k + 3][vl] = t.w;
    }
  }
  __syncthreads();

  float acc[8][8];
#pragma unroll
  for (int i = 0; i < 8; ++i)
#pragma unroll
    for (int j = 0; j < 8; ++j) acc[i][j] = 0.0f;

#pragma unroll 4
  for (int k = 0; k < HID; ++k) {
    const float4 h0 = *(const float4*)&sh[k][ti * 8];
    const float4 h1 = *(const float4*)&sh[k][ti * 8 + 4];
    const float4 w0 = *(const float4*)&sw[k][tj * 4];
    const float4 w1 = *(const float4*)&sw[k][64 + tj * 4];
    const float hv[8] = {h0.x, h0.y, h0.z, h0.w, h1.x, h1.y, h1.z, h1.w};
    const float wv[8] = {w0.x, w0.y, w0.z, w0.w, w1.x, w1.y, w1.z, w1.w};
#pragma unroll
    for (int i = 0; i < 8; ++i)
#pragma unroll
      for (int j = 0; j < 8; ++j) acc[i][j] += hv[i] * wv[j];
  }

#pragma unroll
  for (int i = 0; i < 8; ++i) {
    const size_t row = (size_t)(b0 + ti * 8 + i) * VOCAB;
    float4 o0, o1;
    o0.x = acc[i][0] + bias0.x; o0.y = acc[i][1] + bias0.y;
    o0.z = acc[i][2] + bias0.z; o0.w = acc[i][3] + bias0.w;
    o1.x = acc[i][4] + bias1.x; o1.y = acc[i][5] + bias1.y;
    o1.z = acc[i][6] + bias1.z; o1.w = acc[i][7] + bias1.w;
    *(float4*)&out[row + v0 + tj * 4] = o0;
    *(float4*)&out[row + v0 + 64 + tj * 4] = o1;
  }
}

extern "C" void kernel_launch(void* const* d_in, const int* in_sizes, int n_in,
                              void* d_out, int out_size, void* d_ws, size_t ws_size,
                              hipStream_t stream) {
  const int* x = (const int*)d_in[0];
  const float* emb = (const float*)d_in[1];
  const float* W_ih = (const float*)d_in[2];
  const float* W_hh = (const float*)d_in[3];
  const float* b_ih = (const float*)d_in[4];
  const float* b_hh = (const float*)d_in[5];
  const float* fc_W = (const float*)d_in[6];
  const float* fc_b = (const float*)d_in[7];
  float* out = (float*)d_out;

  // table (32.77 MB) lives in d_out: read only by lstm_mfma, which completes
  // (stream-ordered) before fc_kernel overwrites d_out. h_last in d_ws.
  float* table = out;
  float* hbuf = (float*)d_ws;

  build_table<<<VOCAB / K1_ROWS, 256, 0, stream>>>(emb, W_ih, b_ih, b_hh, table);
  lstm_mfma<<<BATCH / NB, 256, 0, stream>>>(x, table, W_hh, hbuf);
  dim3 g3(VOCAB / FC_BV, BATCH / FC_BB);
  fc_kernel<<<g3, 256, 0, stream>>>(hbuf, fc_W, fc_b, out);
}